// Round 1
// baseline (723.929 us; speedup 1.0000x reference)
//
#include <hip/hip_runtime.h>
#include <math.h>

// ---------------------------------------------------------------------------
// GATConv forward, decomposed:
//   1. k_gemm   : xw = x @ W                       [N,128]
//   2. k_att    : a_src/a_dst = <xw, att_{src,dst}> per head   [N,4]
//   3. k_deg    : degree count by destination (row)
//   4. k_scan   : exclusive scan -> rowptr, fill
//   5. k_scatter: CSR build + alpha = exp(leaky_relu(a_src[row]+a_dst[col]))
//   6. k_agg    : out[n] = sum_e w_e * xw[col_e] / (sum_e w_e + 1e-16)
// Softmax max-subtraction skipped (shift-invariant; logits are O(5), fp32 safe).
// ---------------------------------------------------------------------------

__device__ __forceinline__ float lrelu_exp(float v) {
    v = (v > 0.0f) ? v : 0.2f * v;
    return __expf(v);
}

// ---- 1. GEMM: W staged in LDS (64 KB), x rows broadcast-read from global ----
__global__ __launch_bounds__(256, 2) void k_gemm(const float* __restrict__ x,
                                                 const float* __restrict__ W,
                                                 float* __restrict__ xw, int N) {
    __shared__ float Wl[128 * 128];  // 64 KB
    int t = threadIdx.x;
    for (int i = t; i < 4096; i += 256)
        ((float4*)Wl)[i] = ((const float4*)W)[i];
    __syncthreads();

    int col = t & 127;          // output column
    int rg  = t >> 7;           // row group 0/1 (8 rows each)
    int ntiles = (N + 15) >> 4;
    for (int tile = blockIdx.x; tile < ntiles; tile += gridDim.x) {
        int row0 = tile * 16 + rg * 8;
        int rowc[8];
        #pragma unroll
        for (int r = 0; r < 8; ++r) {
            int row = row0 + r;
            rowc[r] = (row < N) ? row : (N - 1);  // clamp: safe read, store guarded
        }
        float acc[8] = {0, 0, 0, 0, 0, 0, 0, 0};
        #pragma unroll 2
        for (int k = 0; k < 128; k += 4) {
            float w0 = Wl[(k + 0) * 128 + col];
            float w1 = Wl[(k + 1) * 128 + col];
            float w2 = Wl[(k + 2) * 128 + col];
            float w3 = Wl[(k + 3) * 128 + col];
            #pragma unroll
            for (int r = 0; r < 8; ++r) {
                float4 xv = *(const float4*)&x[(size_t)rowc[r] * 128 + k];
                acc[r] = fmaf(xv.x, w0, acc[r]);
                acc[r] = fmaf(xv.y, w1, acc[r]);
                acc[r] = fmaf(xv.z, w2, acc[r]);
                acc[r] = fmaf(xv.w, w3, acc[r]);
            }
        }
        #pragma unroll
        for (int r = 0; r < 8; ++r) {
            int row = row0 + r;
            if (row < N) xw[(size_t)row * 128 + col] = acc[r];
        }
    }
}

// ---- 2. per-node, per-head attention logits (one wave per node) ----
__global__ __launch_bounds__(256) void k_att(const float* __restrict__ xw,
                                             const float* __restrict__ att_src,
                                             const float* __restrict__ att_dst,
                                             float* __restrict__ a_src,
                                             float* __restrict__ a_dst, int N) {
    int lane = threadIdx.x & 63;
    int n = blockIdx.x * 4 + (threadIdx.x >> 6);
    if (n >= N) return;
    int d  = lane & 31;
    int hh = lane >> 5;  // 0 or 1
    #pragma unroll
    for (int g = 0; g < 2; ++g) {
        int h = g * 2 + hh;                 // heads 0..3
        float v  = xw[(size_t)n * 128 + h * 32 + d];
        float ps = v * att_src[h * 32 + d];
        float pd = v * att_dst[h * 32 + d];
        #pragma unroll
        for (int off = 16; off > 0; off >>= 1) {
            ps += __shfl_xor(ps, off);
            pd += __shfl_xor(pd, off);
        }
        if (d == 0) {
            a_src[(size_t)n * 4 + h] = ps;
            a_dst[(size_t)n * 4 + h] = pd;
        }
    }
}

// ---- 3. degree count ----
__global__ __launch_bounds__(256) void k_deg(const int* __restrict__ eidx,
                                             int* __restrict__ deg, int E) {
    int e = blockIdx.x * 256 + threadIdx.x;
    if (e >= E) return;
    atomicAdd(&deg[eidx[e]], 1);
}

// ---- 4. exclusive scan (single block, 1024 threads, 4 elems/thread/iter) ----
__global__ __launch_bounds__(1024) void k_scan(const int* __restrict__ deg,
                                               int* __restrict__ rowptr,
                                               int* __restrict__ fill, int N) {
    __shared__ int wtot[16];
    __shared__ int chunk_total;
    int t = threadIdx.x;
    int lane = t & 63, wv = t >> 6;
    int base = 0;
    for (int start = 0; start < N; start += 4096) {
        int idx = start + t * 4;
        int d0 = 0, d1 = 0, d2 = 0, d3 = 0;
        if (idx + 3 < N) {
            int4 v = *(const int4*)&deg[idx];
            d0 = v.x; d1 = v.y; d2 = v.z; d3 = v.w;
        } else {
            if (idx     < N) d0 = deg[idx];
            if (idx + 1 < N) d1 = deg[idx + 1];
            if (idx + 2 < N) d2 = deg[idx + 2];
        }
        int s = d0 + d1 + d2 + d3;
        int sc = s;  // inclusive wave scan
        #pragma unroll
        for (int off = 1; off < 64; off <<= 1) {
            int v = __shfl_up(sc, off);
            if (lane >= off) sc += v;
        }
        if (lane == 63) wtot[wv] = sc;
        __syncthreads();
        if (t == 0) {
            int run = 0;
            #pragma unroll
            for (int i = 0; i < 16; ++i) { int tmp = wtot[i]; wtot[i] = run; run += tmp; }
            chunk_total = run;
        }
        __syncthreads();
        int excl = base + wtot[wv] + (sc - s);
        if (idx     < N) { rowptr[idx]     = excl;            fill[idx]     = excl; }
        if (idx + 1 < N) { rowptr[idx + 1] = excl + d0;       fill[idx + 1] = excl + d0; }
        if (idx + 2 < N) { rowptr[idx + 2] = excl + d0 + d1;  fill[idx + 2] = excl + d0 + d1; }
        if (idx + 3 < N) { rowptr[idx + 3] = excl + d0 + d1 + d2; fill[idx + 3] = excl + d0 + d1 + d2; }
        base += chunk_total;
        __syncthreads();
    }
    if (t == 0) rowptr[N] = base;
}

// ---- 5. CSR scatter + edge weights ----
__global__ __launch_bounds__(256) void k_scatter(const int* __restrict__ eidx,
                                                 const float* __restrict__ a_src,
                                                 const float* __restrict__ a_dst,
                                                 int* __restrict__ fill,
                                                 int* __restrict__ csr_col,
                                                 float* __restrict__ csr_w, int E) {
    int e = blockIdx.x * 256 + threadIdx.x;
    if (e >= E) return;
    int row = eidx[e];
    int col = eidx[E + e];
    float4 s = *(const float4*)&a_src[(size_t)row * 4];
    float4 d = *(const float4*)&a_dst[(size_t)col * 4];
    float4 w;
    w.x = lrelu_exp(s.x + d.x);
    w.y = lrelu_exp(s.y + d.y);
    w.z = lrelu_exp(s.z + d.z);
    w.w = lrelu_exp(s.w + d.w);
    int pos = atomicAdd(&fill[row], 1);
    csr_col[pos] = col;
    *(float4*)&csr_w[(size_t)pos * 4] = w;
}

// ---- 6. aggregation: one wave per destination node ----
__global__ __launch_bounds__(256) void k_agg(const int* __restrict__ rowptr,
                                             const int* __restrict__ csr_col,
                                             const float* __restrict__ csr_w,
                                             const float* __restrict__ xw,
                                             float* __restrict__ out, int N) {
    int lane = threadIdx.x & 63;
    int n = blockIdx.x * 4 + (threadIdx.x >> 6);
    if (n >= N) return;
    int beg = rowptr[n], end = rowptr[n + 1];
    int h = lane >> 4;  // channel pair (2*lane, 2*lane+1) -> head = 2*lane/32
    float accx = 0.f, accy = 0.f, wsum = 0.f;
    for (int i = beg; i < end; ++i) {
        int col = csr_col[i];
        float w = csr_w[(size_t)i * 4 + h];
        float2 xv = *(const float2*)&xw[(size_t)col * 128 + lane * 2];
        accx = fmaf(w, xv.x, accx);
        accy = fmaf(w, xv.y, accy);
        wsum += w;
    }
    float inv = 1.0f / (wsum + 1e-16f);
    float2 o;
    o.x = accx * inv;
    o.y = accy * inv;
    *(float2*)&out[(size_t)n * 128 + lane * 2] = o;
}

extern "C" void kernel_launch(void* const* d_in, const int* in_sizes, int n_in,
                              void* d_out, int out_size, void* d_ws, size_t ws_size,
                              hipStream_t stream) {
    const float* x       = (const float*)d_in[0];
    const float* W       = (const float*)d_in[1];
    const float* att_src = (const float*)d_in[2];
    const float* att_dst = (const float*)d_in[3];
    // d_in[4] edge_weight: unused by the reference
    const int* eidx      = (const int*)d_in[5];
    int N = in_sizes[0] / 128;
    int E = in_sizes[4];
    float* out = (float*)d_out;

    char* p = (char*)d_ws;
    auto alloc = [&](size_t bytes) {
        char* r = p;
        p += (bytes + 255) & ~(size_t)255;
        return r;
    };
    float* xw     = (float*)alloc((size_t)N * 128 * 4);
    float* a_src  = (float*)alloc((size_t)N * 4 * 4);
    float* a_dst  = (float*)alloc((size_t)N * 4 * 4);
    int*   deg    = (int*)  alloc((size_t)N * 4);
    int*   rowptr = (int*)  alloc((size_t)(N + 1) * 4);
    int*   fill   = (int*)  alloc((size_t)N * 4);
    int*   csr_col= (int*)  alloc((size_t)E * 4);
    float* csr_w  = (float*)alloc((size_t)E * 16);

    hipMemsetAsync(deg, 0, (size_t)N * 4, stream);
    k_gemm<<<1024, 256, 0, stream>>>(x, W, xw, N);
    k_att<<<(N + 3) / 4, 256, 0, stream>>>(xw, att_src, att_dst, a_src, a_dst, N);
    k_deg<<<(E + 255) / 256, 256, 0, stream>>>(eidx, deg, E);
    k_scan<<<1, 1024, 0, stream>>>(deg, rowptr, fill, N);
    k_scatter<<<(E + 255) / 256, 256, 0, stream>>>(eidx, a_src, a_dst, fill, csr_col, csr_w, E);
    k_agg<<<(N + 3) / 4, 256, 0, stream>>>(rowptr, csr_col, csr_w, xw, out, N);
}

// Round 2
// 515.691 us; speedup vs baseline: 1.4038x; 1.4038x over previous
//
#include <hip/hip_runtime.h>
#include <math.h>

// ---------------------------------------------------------------------------
// GATConv forward:
//   1. k_gemm   : xw = x @ W  (LDS-tiled, fused per-head att logits a_src/a_dst)
//   2. k_deg    : degree count by destination (row)
//   3. k_scan   : exclusive scan -> rowptr, fill (single block, 16 elems/thread)
//   4. k_scatter: CSR build + alpha = exp(leaky_relu(a_src[row]+a_dst[col]))
//   5. k_agg    : out[n] = sum_e w_e * xw[col_e] / (sum_e w_e + 1e-16)
// Softmax max-subtraction skipped (shift-invariant; logits are O(5), fp32 safe).
// ---------------------------------------------------------------------------

__device__ __forceinline__ float lrelu_exp(float v) {
    v = (v > 0.0f) ? v : 0.2f * v;
    return __expf(v);
}

// ---- 1. GEMM: 64 rows x 128 cols per block, K-chunk 32, fused attention ----
// xT stride 68: 16B-aligned rows (68%4==0) and transpose-write conflicts
// limited to 4-way; compute-side reads are 2-address broadcast (free).
__global__ __launch_bounds__(256) void k_gemm(const float* __restrict__ x,
                                              const float* __restrict__ W,
                                              const float* __restrict__ att_src,
                                              const float* __restrict__ att_dst,
                                              float* __restrict__ xw,
                                              float* __restrict__ a_src,
                                              float* __restrict__ a_dst, int N) {
    __shared__ float Ws[32][128];   // 16 KB
    __shared__ float xT[32][68];    // 8.5 KB
    int t = threadIdx.x;
    int tx = t & 31;   // col group: cols 4*tx..4*tx+3
    int ty = t >> 5;   // row group: rows 8*ty..8*ty+7
    int row0 = blockIdx.x * 64;

    float acc[8][4];
    #pragma unroll
    for (int r = 0; r < 8; ++r)
        #pragma unroll
        for (int j = 0; j < 4; ++j) acc[r][j] = 0.f;

    for (int kc = 0; kc < 128; kc += 32) {
        __syncthreads();  // previous chunk's reads done before overwrite
        // stage W chunk [kc..kc+31][0..127], coalesced float4
        #pragma unroll
        for (int i = 0; i < 4; ++i) {
            int fi = i * 256 + t;                 // float4 idx 0..1023
            int kl = fi >> 5, c4 = (fi & 31) << 2;
            *(float4*)&Ws[kl][c4] = *(const float4*)&W[(size_t)(kc + kl) * 128 + c4];
        }
        // stage x chunk transposed: rows row0..row0+63, k kc..kc+31
        #pragma unroll
        for (int i = 0; i < 2; ++i) {
            int fi = i * 256 + t;                 // 0..511
            int r = fi >> 3, kq = (fi & 7) << 2;
            int grow = row0 + r; if (grow >= N) grow = N - 1;  // clamp (store guarded)
            float4 v = *(const float4*)&x[(size_t)grow * 128 + kc + kq];
            xT[kq + 0][r] = v.x;
            xT[kq + 1][r] = v.y;
            xT[kq + 2][r] = v.z;
            xT[kq + 3][r] = v.w;
        }
        __syncthreads();
        #pragma unroll 8
        for (int k = 0; k < 32; ++k) {
            float4 wv = *(const float4*)&Ws[k][tx << 2];
            float4 xa = *(const float4*)&xT[k][ty << 3];
            float4 xb = *(const float4*)&xT[k][(ty << 3) + 4];
            float xr[8] = {xa.x, xa.y, xa.z, xa.w, xb.x, xb.y, xb.z, xb.w};
            #pragma unroll
            for (int r = 0; r < 8; ++r) {
                acc[r][0] = fmaf(xr[r], wv.x, acc[r][0]);
                acc[r][1] = fmaf(xr[r], wv.y, acc[r][1]);
                acc[r][2] = fmaf(xr[r], wv.z, acc[r][2]);
                acc[r][3] = fmaf(xr[r], wv.w, acc[r][3]);
            }
        }
    }

    // epilogue: store xw + fused per-head attention logits
    int h  = tx >> 3;           // head 0..3 (cols 32h..32h+31)
    int dq = (tx & 7) << 2;     // d offset within head
    float4 as = *(const float4*)&att_src[h * 32 + dq];
    float4 ad = *(const float4*)&att_dst[h * 32 + dq];
    #pragma unroll
    for (int r = 0; r < 8; ++r) {
        int row = row0 + (ty << 3) + r;
        bool ok = row < N;
        if (ok) *(float4*)&xw[(size_t)row * 128 + (tx << 2)] = *(float4*)acc[r];
        float ps = acc[r][0] * as.x + acc[r][1] * as.y + acc[r][2] * as.z + acc[r][3] * as.w;
        float pd = acc[r][0] * ad.x + acc[r][1] * ad.y + acc[r][2] * ad.z + acc[r][3] * ad.w;
        ps += __shfl_xor(ps, 1); pd += __shfl_xor(pd, 1);
        ps += __shfl_xor(ps, 2); pd += __shfl_xor(pd, 2);
        ps += __shfl_xor(ps, 4); pd += __shfl_xor(pd, 4);
        if (ok && (tx & 7) == 0) {
            a_src[(size_t)row * 4 + h] = ps;
            a_dst[(size_t)row * 4 + h] = pd;
        }
    }
}

// ---- 2. degree count ----
__global__ __launch_bounds__(256) void k_deg(const int* __restrict__ eidx,
                                             int* __restrict__ deg, int E) {
    int e = blockIdx.x * 256 + threadIdx.x;
    if (e >= E) return;
    atomicAdd(&deg[eidx[e]], 1);
}

// ---- 3. exclusive scan (single block, 1024 thr, 16 elems/thread/iter) ----
__global__ __launch_bounds__(1024) void k_scan(const int* __restrict__ deg,
                                               int* __restrict__ rowptr,
                                               int* __restrict__ fill, int N) {
    __shared__ int wtot[16];
    __shared__ int chunk_total;
    int t = threadIdx.x;
    int lane = t & 63, wv = t >> 6;
    int base = 0;
    for (int start = 0; start < N; start += 16384) {
        int idx = start + t * 16;
        int d[16];
        #pragma unroll
        for (int q = 0; q < 4; ++q) {
            int i0 = idx + q * 4;
            if (i0 + 3 < N) {
                int4 v = *(const int4*)&deg[i0];
                d[q * 4 + 0] = v.x; d[q * 4 + 1] = v.y;
                d[q * 4 + 2] = v.z; d[q * 4 + 3] = v.w;
            } else {
                #pragma unroll
                for (int j = 0; j < 4; ++j) d[q * 4 + j] = (i0 + j < N) ? deg[i0 + j] : 0;
            }
        }
        int s = 0;
        #pragma unroll
        for (int i = 0; i < 16; ++i) s += d[i];
        int sc = s;  // inclusive wave scan
        #pragma unroll
        for (int off = 1; off < 64; off <<= 1) {
            int v = __shfl_up(sc, off);
            if (lane >= off) sc += v;
        }
        if (lane == 63) wtot[wv] = sc;
        __syncthreads();
        if (t == 0) {
            int run = 0;
            #pragma unroll
            for (int i = 0; i < 16; ++i) { int tmp = wtot[i]; wtot[i] = run; run += tmp; }
            chunk_total = run;
        }
        __syncthreads();
        int run = base + wtot[wv] + (sc - s);
        int pfx[16];
        #pragma unroll
        for (int i = 0; i < 16; ++i) { pfx[i] = run; run += d[i]; }
        #pragma unroll
        for (int q = 0; q < 4; ++q) {
            int i0 = idx + q * 4;
            if (i0 + 3 < N) {
                int4 v = make_int4(pfx[q * 4], pfx[q * 4 + 1], pfx[q * 4 + 2], pfx[q * 4 + 3]);
                *(int4*)&rowptr[i0] = v;
                *(int4*)&fill[i0]   = v;
            } else {
                #pragma unroll
                for (int j = 0; j < 4; ++j)
                    if (i0 + j < N) { rowptr[i0 + j] = pfx[q * 4 + j]; fill[i0 + j] = pfx[q * 4 + j]; }
            }
        }
        base += chunk_total;
        __syncthreads();
    }
    if (t == 0) rowptr[N] = base;
}

// ---- 4. CSR scatter + edge weights ----
__global__ __launch_bounds__(256) void k_scatter(const int* __restrict__ eidx,
                                                 const float* __restrict__ a_src,
                                                 const float* __restrict__ a_dst,
                                                 int* __restrict__ fill,
                                                 int* __restrict__ csr_col,
                                                 float* __restrict__ csr_w, int E) {
    int e = blockIdx.x * 256 + threadIdx.x;
    if (e >= E) return;
    int row = eidx[e];
    int col = eidx[E + e];
    float4 s = *(const float4*)&a_src[(size_t)row * 4];
    float4 d = *(const float4*)&a_dst[(size_t)col * 4];
    float4 w;
    w.x = lrelu_exp(s.x + d.x);
    w.y = lrelu_exp(s.y + d.y);
    w.z = lrelu_exp(s.z + d.z);
    w.w = lrelu_exp(s.w + d.w);
    int pos = atomicAdd(&fill[row], 1);
    csr_col[pos] = col;
    *(float4*)&csr_w[(size_t)pos * 4] = w;
}

// ---- 5. aggregation: one wave per destination node ----
__global__ __launch_bounds__(256) void k_agg(const int* __restrict__ rowptr,
                                             const int* __restrict__ csr_col,
                                             const float* __restrict__ csr_w,
                                             const float* __restrict__ xw,
                                             float* __restrict__ out, int N) {
    int lane = threadIdx.x & 63;
    int n = blockIdx.x * 4 + (threadIdx.x >> 6);
    if (n >= N) return;
    int beg = rowptr[n], end = rowptr[n + 1];
    int h = lane >> 4;  // head for this channel pair
    float accx = 0.f, accy = 0.f, wsum = 0.f;
    for (int i = beg; i < end; ++i) {
        int col = csr_col[i];
        float w = csr_w[(size_t)i * 4 + h];
        float2 xv = *(const float2*)&xw[(size_t)col * 128 + lane * 2];
        accx = fmaf(w, xv.x, accx);
        accy = fmaf(w, xv.y, accy);
        wsum += w;
    }
    float inv = 1.0f / (wsum + 1e-16f);
    float2 o;
    o.x = accx * inv;
    o.y = accy * inv;
    *(float2*)&out[(size_t)n * 128 + lane * 2] = o;
}

extern "C" void kernel_launch(void* const* d_in, const int* in_sizes, int n_in,
                              void* d_out, int out_size, void* d_ws, size_t ws_size,
                              hipStream_t stream) {
    const float* x       = (const float*)d_in[0];
    const float* W       = (const float*)d_in[1];
    const float* att_src = (const float*)d_in[2];
    const float* att_dst = (const float*)d_in[3];
    // d_in[4] edge_weight: unused by the reference
    const int* eidx      = (const int*)d_in[5];
    int N = in_sizes[0] / 128;
    int E = in_sizes[4];
    float* out = (float*)d_out;

    char* p = (char*)d_ws;
    auto alloc = [&](size_t bytes) {
        char* r = p;
        p += (bytes + 255) & ~(size_t)255;
        return r;
    };
    float* xw      = (float*)alloc((size_t)N * 128 * 4);
    float* a_src   = (float*)alloc((size_t)N * 4 * 4);
    float* a_dst   = (float*)alloc((size_t)N * 4 * 4);
    int*   deg     = (int*)  alloc((size_t)N * 4);
    int*   rowptr  = (int*)  alloc((size_t)(N + 1) * 4);
    int*   fill    = (int*)  alloc((size_t)N * 4);
    int*   csr_col = (int*)  alloc((size_t)E * 4);
    float* csr_w   = (float*)alloc((size_t)E * 16);

    hipMemsetAsync(deg, 0, (size_t)N * 4, stream);
    k_gemm<<<(N + 63) / 64, 256, 0, stream>>>(x, W, att_src, att_dst, xw, a_src, a_dst, N);
    k_deg<<<(E + 255) / 256, 256, 0, stream>>>(eidx, deg, E);
    k_scan<<<1, 1024, 0, stream>>>(deg, rowptr, fill, N);
    k_scatter<<<(E + 255) / 256, 256, 0, stream>>>(eidx, a_src, a_dst, fill, csr_col, csr_w, E);
    k_agg<<<(N + 3) / 4, 256, 0, stream>>>(rowptr, csr_col, csr_w, xw, out, N);
}

// Round 3
// 462.391 us; speedup vs baseline: 1.5656x; 1.1153x over previous
//
#include <hip/hip_runtime.h>
#include <math.h>

// ---------------------------------------------------------------------------
// GATConv forward:
//   1. k_gemm   : xw = x @ W (LDS-tiled; epilogue stores fp16 xw + fused
//                 per-head attention logits a_src/a_dst in fp32)
//   2. k_deg    : degree count by destination (row)
//   3. k_scan   : exclusive scan -> rowptr, fill (single block)
//   4. k_scatter: CSR col-index build only (alpha recomputed in k_agg)
//   5. k_agg    : out[n] = sum_e w_e * xw[col_e] / (sum_e w_e + 1e-16),
//                 w_e = exp(leaky_relu(a_src[n]+a_dst[col_e])) on the fly,
//                 2 edges/wave/iter (half-wave each), unrolled x2.
// Softmax max-subtraction skipped (shift-invariant; logits are O(5), fp32 safe).
// xw stored fp16: |xw|~N(0,1), rel err 5e-4 << bf16-level output threshold.
// ---------------------------------------------------------------------------

typedef _Float16 half4 __attribute__((ext_vector_type(4)));

__device__ __forceinline__ float lrelu_exp(float v) {
    v = (v > 0.0f) ? v : 0.2f * v;
    return __expf(v);
}

// ---- 1. GEMM: 64 rows x 128 cols per block, K-chunk 32, fused attention ----
__global__ __launch_bounds__(256) void k_gemm(const float* __restrict__ x,
                                              const float* __restrict__ W,
                                              const float* __restrict__ att_src,
                                              const float* __restrict__ att_dst,
                                              _Float16* __restrict__ xwh,
                                              float* __restrict__ a_src,
                                              float* __restrict__ a_dst, int N) {
    __shared__ float Ws[32][128];   // 16 KB
    __shared__ float xT[32][68];    // 8.5 KB
    int t = threadIdx.x;
    int tx = t & 31;   // col group: cols 4*tx..4*tx+3
    int ty = t >> 5;   // row group: rows 8*ty..8*ty+7
    int row0 = blockIdx.x * 64;

    float acc[8][4];
    #pragma unroll
    for (int r = 0; r < 8; ++r)
        #pragma unroll
        for (int j = 0; j < 4; ++j) acc[r][j] = 0.f;

    for (int kc = 0; kc < 128; kc += 32) {
        __syncthreads();
        #pragma unroll
        for (int i = 0; i < 4; ++i) {
            int fi = i * 256 + t;
            int kl = fi >> 5, c4 = (fi & 31) << 2;
            *(float4*)&Ws[kl][c4] = *(const float4*)&W[(size_t)(kc + kl) * 128 + c4];
        }
        #pragma unroll
        for (int i = 0; i < 2; ++i) {
            int fi = i * 256 + t;
            int r = fi >> 3, kq = (fi & 7) << 2;
            int grow = row0 + r; if (grow >= N) grow = N - 1;
            float4 v = *(const float4*)&x[(size_t)grow * 128 + kc + kq];
            xT[kq + 0][r] = v.x;
            xT[kq + 1][r] = v.y;
            xT[kq + 2][r] = v.z;
            xT[kq + 3][r] = v.w;
        }
        __syncthreads();
        #pragma unroll 8
        for (int k = 0; k < 32; ++k) {
            float4 wv = *(const float4*)&Ws[k][tx << 2];
            float4 xa = *(const float4*)&xT[k][ty << 3];
            float4 xb = *(const float4*)&xT[k][(ty << 3) + 4];
            float xr[8] = {xa.x, xa.y, xa.z, xa.w, xb.x, xb.y, xb.z, xb.w};
            #pragma unroll
            for (int r = 0; r < 8; ++r) {
                acc[r][0] = fmaf(xr[r], wv.x, acc[r][0]);
                acc[r][1] = fmaf(xr[r], wv.y, acc[r][1]);
                acc[r][2] = fmaf(xr[r], wv.z, acc[r][2]);
                acc[r][3] = fmaf(xr[r], wv.w, acc[r][3]);
            }
        }
    }

    // epilogue: store fp16 xw + fused per-head attention logits (fp32)
    int h  = tx >> 3;
    int dq = (tx & 7) << 2;
    float4 as = *(const float4*)&att_src[h * 32 + dq];
    float4 ad = *(const float4*)&att_dst[h * 32 + dq];
    #pragma unroll
    for (int r = 0; r < 8; ++r) {
        int row = row0 + (ty << 3) + r;
        bool ok = row < N;
        if (ok) {
            half4 hv;
            hv.x = (_Float16)acc[r][0];
            hv.y = (_Float16)acc[r][1];
            hv.z = (_Float16)acc[r][2];
            hv.w = (_Float16)acc[r][3];
            *(half4*)&xwh[(size_t)row * 128 + (tx << 2)] = hv;
        }
        float ps = acc[r][0] * as.x + acc[r][1] * as.y + acc[r][2] * as.z + acc[r][3] * as.w;
        float pd = acc[r][0] * ad.x + acc[r][1] * ad.y + acc[r][2] * ad.z + acc[r][3] * ad.w;
        ps += __shfl_xor(ps, 1); pd += __shfl_xor(pd, 1);
        ps += __shfl_xor(ps, 2); pd += __shfl_xor(pd, 2);
        ps += __shfl_xor(ps, 4); pd += __shfl_xor(pd, 4);
        if (ok && (tx & 7) == 0) {
            a_src[(size_t)row * 4 + h] = ps;
            a_dst[(size_t)row * 4 + h] = pd;
        }
    }
}

// ---- 2. degree count ----
__global__ __launch_bounds__(256) void k_deg(const int* __restrict__ eidx,
                                             int* __restrict__ deg, int E) {
    int e = blockIdx.x * 256 + threadIdx.x;
    if (e >= E) return;
    atomicAdd(&deg[eidx[e]], 1);
}

// ---- 3. exclusive scan (single block, 1024 thr, 16 elems/thread/iter) ----
__global__ __launch_bounds__(1024) void k_scan(const int* __restrict__ deg,
                                               int* __restrict__ rowptr,
                                               int* __restrict__ fill, int N) {
    __shared__ int wtot[16];
    __shared__ int chunk_total;
    int t = threadIdx.x;
    int lane = t & 63, wv = t >> 6;
    int base = 0;
    for (int start = 0; start < N; start += 16384) {
        int idx = start + t * 16;
        int d[16];
        #pragma unroll
        for (int q = 0; q < 4; ++q) {
            int i0 = idx + q * 4;
            if (i0 + 3 < N) {
                int4 v = *(const int4*)&deg[i0];
                d[q * 4 + 0] = v.x; d[q * 4 + 1] = v.y;
                d[q * 4 + 2] = v.z; d[q * 4 + 3] = v.w;
            } else {
                #pragma unroll
                for (int j = 0; j < 4; ++j) d[q * 4 + j] = (i0 + j < N) ? deg[i0 + j] : 0;
            }
        }
        int s = 0;
        #pragma unroll
        for (int i = 0; i < 16; ++i) s += d[i];
        int sc = s;
        #pragma unroll
        for (int off = 1; off < 64; off <<= 1) {
            int v = __shfl_up(sc, off);
            if (lane >= off) sc += v;
        }
        if (lane == 63) wtot[wv] = sc;
        __syncthreads();
        if (t == 0) {
            int run = 0;
            #pragma unroll
            for (int i = 0; i < 16; ++i) { int tmp = wtot[i]; wtot[i] = run; run += tmp; }
            chunk_total = run;
        }
        __syncthreads();
        int run = base + wtot[wv] + (sc - s);
        int pfx[16];
        #pragma unroll
        for (int i = 0; i < 16; ++i) { pfx[i] = run; run += d[i]; }
        #pragma unroll
        for (int q = 0; q < 4; ++q) {
            int i0 = idx + q * 4;
            if (i0 + 3 < N) {
                int4 v = make_int4(pfx[q * 4], pfx[q * 4 + 1], pfx[q * 4 + 2], pfx[q * 4 + 3]);
                *(int4*)&rowptr[i0] = v;
                *(int4*)&fill[i0]   = v;
            } else {
                #pragma unroll
                for (int j = 0; j < 4; ++j)
                    if (i0 + j < N) { rowptr[i0 + j] = pfx[q * 4 + j]; fill[i0 + j] = pfx[q * 4 + j]; }
            }
        }
        base += chunk_total;
        __syncthreads();
    }
    if (t == 0) rowptr[N] = base;
}

// ---- 4. CSR col-index build ----
__global__ __launch_bounds__(256) void k_scatter(const int* __restrict__ eidx,
                                                 int* __restrict__ fill,
                                                 int* __restrict__ csr_col, int E) {
    int e = blockIdx.x * 256 + threadIdx.x;
    if (e >= E) return;
    int row = eidx[e];
    int col = eidx[E + e];
    int pos = atomicAdd(&fill[row], 1);
    csr_col[pos] = col;
}

// ---- 5. aggregation: one wave per node, 2 edges/iter (half-wave each), x2 ----
__global__ __launch_bounds__(256) void k_agg(const int* __restrict__ rowptr,
                                             const int* __restrict__ csr_col,
                                             const float* __restrict__ a_src,
                                             const float* __restrict__ a_dst,
                                             const _Float16* __restrict__ xwh,
                                             float* __restrict__ out, int N) {
    int lane = threadIdx.x & 63;
    int n = blockIdx.x * 4 + (threadIdx.x >> 6);
    if (n >= N) return;
    int beg = rowptr[n], end = rowptr[n + 1];
    int halfid = lane >> 5;
    int l = lane & 31;        // channels 4l..4l+3
    int h = l >> 3;           // head
    float s_n = a_src[(size_t)n * 4 + h];
    float ax = 0.f, ay = 0.f, az = 0.f, aw = 0.f, ws = 0.f;
    int last = end - 1;
    for (int i = beg; i < end; i += 4) {
        int e0 = i + halfid;
        int e1 = i + 2 + halfid;
        int e0c = e0 <= last ? e0 : last;
        int e1c = e1 <= last ? e1 : last;
        float m0 = e0 <= last ? 1.f : 0.f;
        float m1 = e1 <= last ? 1.f : 0.f;
        int c0 = csr_col[e0c];
        int c1 = csr_col[e1c];
        float w0 = m0 * lrelu_exp(s_n + a_dst[(size_t)c0 * 4 + h]);
        float w1 = m1 * lrelu_exp(s_n + a_dst[(size_t)c1 * 4 + h]);
        half4 x0 = *(const half4*)&xwh[(size_t)c0 * 128 + (l << 2)];
        half4 x1 = *(const half4*)&xwh[(size_t)c1 * 128 + (l << 2)];
        ax += w0 * (float)x0.x + w1 * (float)x1.x;
        ay += w0 * (float)x0.y + w1 * (float)x1.y;
        az += w0 * (float)x0.z + w1 * (float)x1.z;
        aw += w0 * (float)x0.w + w1 * (float)x1.w;
        ws += w0 + w1;
    }
    // combine half-waves
    ax += __shfl_xor(ax, 32);
    ay += __shfl_xor(ay, 32);
    az += __shfl_xor(az, 32);
    aw += __shfl_xor(aw, 32);
    ws += __shfl_xor(ws, 32);
    if (halfid == 0) {
        float inv = 1.0f / (ws + 1e-16f);
        float4 o = {ax * inv, ay * inv, az * inv, aw * inv};
        *(float4*)&out[(size_t)n * 128 + (l << 2)] = o;
    }
}

extern "C" void kernel_launch(void* const* d_in, const int* in_sizes, int n_in,
                              void* d_out, int out_size, void* d_ws, size_t ws_size,
                              hipStream_t stream) {
    const float* x       = (const float*)d_in[0];
    const float* W       = (const float*)d_in[1];
    const float* att_src = (const float*)d_in[2];
    const float* att_dst = (const float*)d_in[3];
    // d_in[4] edge_weight: unused by the reference
    const int* eidx      = (const int*)d_in[5];
    int N = in_sizes[0] / 128;
    int E = in_sizes[4];
    float* out = (float*)d_out;

    char* p = (char*)d_ws;
    auto alloc = [&](size_t bytes) {
        char* r = p;
        p += (bytes + 255) & ~(size_t)255;
        return r;
    };
    _Float16* xwh  = (_Float16*)alloc((size_t)N * 128 * 2);
    float* a_src   = (float*)alloc((size_t)N * 4 * 4);
    float* a_dst   = (float*)alloc((size_t)N * 4 * 4);
    int*   deg     = (int*)  alloc((size_t)N * 4);
    int*   rowptr  = (int*)  alloc((size_t)(N + 1) * 4);
    int*   fill    = (int*)  alloc((size_t)N * 4);
    int*   csr_col = (int*)  alloc((size_t)E * 4);

    hipMemsetAsync(deg, 0, (size_t)N * 4, stream);
    k_gemm<<<(N + 63) / 64, 256, 0, stream>>>(x, W, att_src, att_dst, xwh, a_src, a_dst, N);
    k_deg<<<(E + 255) / 256, 256, 0, stream>>>(eidx, deg, E);
    k_scan<<<1, 1024, 0, stream>>>(deg, rowptr, fill, N);
    k_scatter<<<(E + 255) / 256, 256, 0, stream>>>(eidx, fill, csr_col, E);
    k_agg<<<(N + 3) / 4, 256, 0, stream>>>(rowptr, csr_col, a_src, a_dst, xwh, out, N);
}

// Round 4
// 362.374 us; speedup vs baseline: 1.9977x; 1.2760x over previous
//
#include <hip/hip_runtime.h>
#include <math.h>

// ---------------------------------------------------------------------------
// GATConv forward:
//   1. k_gemm : xw = x @ W (LDS-tiled; epilogue: fp16 xw + fused att logits)
//   2. k_deg  : degree count by row; atomicAdd return value = per-edge rank
//               within its row (stored in erank) -> no fill atomics later
//   3. k_scan : exclusive scan -> rowptr; tail initializes bucket cursors
//   4. k_part : partition edges into 512-row buckets (LDS histogram, coalesced
//               int2 record writes)  [kills the 16x scattered-write ampl.]
//   5. k_csr  : per-bucket: csr_col[rowptr[row]+rank] = col  (scatter confined
//               to ~32 KB window -> L2-absorbed)
//   6. k_agg  : out[n] = sum_e w_e*xw[col_e] / (sum_e w_e + 1e-16),
//               w_e = exp(leaky_relu(a_src[n]+a_dst[col_e])) on the fly,
//               half8 loads, 4 edge slots/wave, unrolled x2 (8 chains).
// Softmax max-subtraction skipped (shift-invariant; logits are O(5), fp32 safe).
// ---------------------------------------------------------------------------

typedef _Float16 half4 __attribute__((ext_vector_type(4)));
typedef _Float16 half8 __attribute__((ext_vector_type(8)));

__device__ __forceinline__ float lrelu_exp(float v) {
    v = (v > 0.0f) ? v : 0.2f * v;
    return __expf(v);
}

// ---- 1. GEMM: 64 rows x 128 cols per block, K-chunk 32, fused attention ----
__global__ __launch_bounds__(256) void k_gemm(const float* __restrict__ x,
                                              const float* __restrict__ W,
                                              const float* __restrict__ att_src,
                                              const float* __restrict__ att_dst,
                                              _Float16* __restrict__ xwh,
                                              float* __restrict__ a_src,
                                              float* __restrict__ a_dst, int N) {
    __shared__ float Ws[32][128];   // 16 KB
    __shared__ float xT[32][68];    // 8.5 KB
    int t = threadIdx.x;
    int tx = t & 31;   // col group: cols 4*tx..4*tx+3
    int ty = t >> 5;   // row group: rows 8*ty..8*ty+7
    int row0 = blockIdx.x * 64;

    float acc[8][4];
    #pragma unroll
    for (int r = 0; r < 8; ++r)
        #pragma unroll
        for (int j = 0; j < 4; ++j) acc[r][j] = 0.f;

    for (int kc = 0; kc < 128; kc += 32) {
        __syncthreads();
        #pragma unroll
        for (int i = 0; i < 4; ++i) {
            int fi = i * 256 + t;
            int kl = fi >> 5, c4 = (fi & 31) << 2;
            *(float4*)&Ws[kl][c4] = *(const float4*)&W[(size_t)(kc + kl) * 128 + c4];
        }
        #pragma unroll
        for (int i = 0; i < 2; ++i) {
            int fi = i * 256 + t;
            int r = fi >> 3, kq = (fi & 7) << 2;
            int grow = row0 + r; if (grow >= N) grow = N - 1;
            float4 v = *(const float4*)&x[(size_t)grow * 128 + kc + kq];
            xT[kq + 0][r] = v.x;
            xT[kq + 1][r] = v.y;
            xT[kq + 2][r] = v.z;
            xT[kq + 3][r] = v.w;
        }
        __syncthreads();
        #pragma unroll 8
        for (int k = 0; k < 32; ++k) {
            float4 wv = *(const float4*)&Ws[k][tx << 2];
            float4 xa = *(const float4*)&xT[k][ty << 3];
            float4 xb = *(const float4*)&xT[k][(ty << 3) + 4];
            float xr[8] = {xa.x, xa.y, xa.z, xa.w, xb.x, xb.y, xb.z, xb.w};
            #pragma unroll
            for (int r = 0; r < 8; ++r) {
                acc[r][0] = fmaf(xr[r], wv.x, acc[r][0]);
                acc[r][1] = fmaf(xr[r], wv.y, acc[r][1]);
                acc[r][2] = fmaf(xr[r], wv.z, acc[r][2]);
                acc[r][3] = fmaf(xr[r], wv.w, acc[r][3]);
            }
        }
    }

    int h  = tx >> 3;
    int dq = (tx & 7) << 2;
    float4 as = *(const float4*)&att_src[h * 32 + dq];
    float4 ad = *(const float4*)&att_dst[h * 32 + dq];
    #pragma unroll
    for (int r = 0; r < 8; ++r) {
        int row = row0 + (ty << 3) + r;
        bool ok = row < N;
        if (ok) {
            half4 hv;
            hv.x = (_Float16)acc[r][0];
            hv.y = (_Float16)acc[r][1];
            hv.z = (_Float16)acc[r][2];
            hv.w = (_Float16)acc[r][3];
            *(half4*)&xwh[(size_t)row * 128 + (tx << 2)] = hv;
        }
        float ps = acc[r][0] * as.x + acc[r][1] * as.y + acc[r][2] * as.z + acc[r][3] * as.w;
        float pd = acc[r][0] * ad.x + acc[r][1] * ad.y + acc[r][2] * ad.z + acc[r][3] * ad.w;
        ps += __shfl_xor(ps, 1); pd += __shfl_xor(pd, 1);
        ps += __shfl_xor(ps, 2); pd += __shfl_xor(pd, 2);
        ps += __shfl_xor(ps, 4); pd += __shfl_xor(pd, 4);
        if (ok && (tx & 7) == 0) {
            a_src[(size_t)row * 4 + h] = ps;
            a_dst[(size_t)row * 4 + h] = pd;
        }
    }
}

// ---- 2. degree count + per-edge rank within row ----
__global__ __launch_bounds__(256) void k_deg(const int* __restrict__ eidx,
                                             int* __restrict__ deg,
                                             unsigned short* __restrict__ erank, int E) {
    int e = blockIdx.x * 256 + threadIdx.x;
    if (e >= E) return;
    int r = atomicAdd(&deg[eidx[e]], 1);
    erank[e] = (unsigned short)r;
}

// ---- 3. exclusive scan (single block) + bucket cursor init ----
__global__ __launch_bounds__(1024) void k_scan(const int* __restrict__ deg,
                                               int* __restrict__ rowptr,
                                               int* __restrict__ bcur, int N) {
    __shared__ int wtot[16];
    __shared__ int chunk_total;
    int t = threadIdx.x;
    int lane = t & 63, wv = t >> 6;
    int base = 0;
    for (int start = 0; start < N; start += 16384) {
        int idx = start + t * 16;
        int d[16];
        #pragma unroll
        for (int q = 0; q < 4; ++q) {
            int i0 = idx + q * 4;
            if (i0 + 3 < N) {
                int4 v = *(const int4*)&deg[i0];
                d[q * 4 + 0] = v.x; d[q * 4 + 1] = v.y;
                d[q * 4 + 2] = v.z; d[q * 4 + 3] = v.w;
            } else {
                #pragma unroll
                for (int j = 0; j < 4; ++j) d[q * 4 + j] = (i0 + j < N) ? deg[i0 + j] : 0;
            }
        }
        int s = 0;
        #pragma unroll
        for (int i = 0; i < 16; ++i) s += d[i];
        int sc = s;
        #pragma unroll
        for (int off = 1; off < 64; off <<= 1) {
            int v = __shfl_up(sc, off);
            if (lane >= off) sc += v;
        }
        if (lane == 63) wtot[wv] = sc;
        __syncthreads();
        if (t == 0) {
            int run = 0;
            #pragma unroll
            for (int i = 0; i < 16; ++i) { int tmp = wtot[i]; wtot[i] = run; run += tmp; }
            chunk_total = run;
        }
        __syncthreads();
        int run = base + wtot[wv] + (sc - s);
        int pfx[16];
        #pragma unroll
        for (int i = 0; i < 16; ++i) { pfx[i] = run; run += d[i]; }
        #pragma unroll
        for (int q = 0; q < 4; ++q) {
            int i0 = idx + q * 4;
            if (i0 + 3 < N) {
                *(int4*)&rowptr[i0] =
                    make_int4(pfx[q * 4], pfx[q * 4 + 1], pfx[q * 4 + 2], pfx[q * 4 + 3]);
            } else {
                #pragma unroll
                for (int j = 0; j < 4; ++j)
                    if (i0 + j < N) rowptr[i0 + j] = pfx[q * 4 + j];
            }
        }
        base += chunk_total;
        __syncthreads();
    }
    if (t == 0) rowptr[N] = base;
    __syncthreads();
    if (t < 256) {
        int rs = t << 9; if (rs > N) rs = N;
        bcur[t] = rowptr[rs];
    }
}

// ---- 4. partition edges into 512-row buckets, coalesced record writes ----
#define PCHUNK 4096
__global__ __launch_bounds__(256) void k_part(const int* __restrict__ eidx,
                                              const unsigned short* __restrict__ erank,
                                              int* __restrict__ bcur,
                                              int2* __restrict__ rec, int E) {
    __shared__ int hist[256];
    __shared__ int base[256];
    int t = threadIdx.x;
    int e0 = blockIdx.x * PCHUNK;
    int nE = E - e0; if (nE > PCHUNK) nE = PCHUNK;
    hist[t] = 0;
    __syncthreads();
    for (int i = t; i < nE; i += 256)
        atomicAdd(&hist[eidx[e0 + i] >> 9], 1);
    __syncthreads();
    int cnt = hist[t];
    base[t] = atomicAdd(&bcur[t], cnt);
    hist[t] = 0;
    __syncthreads();
    for (int i = t; i < nE; i += 256) {
        int e = e0 + i;
        int row = eidx[e];
        int col = eidx[E + e];
        int b = row >> 9;
        int lr = atomicAdd(&hist[b], 1);
        rec[base[b] + lr] = make_int2(row | ((int)erank[e] << 17), col);
    }
}

// ---- 5. per-bucket CSR finalize: scatter confined to ~32 KB window ----
__global__ __launch_bounds__(256) void k_csr(const int2* __restrict__ rec,
                                             const int* __restrict__ rowptr,
                                             int* __restrict__ csr_col, int N) {
    int b = blockIdx.x;
    int rs = b << 9;
    if (rs >= N) return;
    int re = rs + 512; if (re > N) re = N;
    int start = rowptr[rs], end = rowptr[re];
    for (int i = start + threadIdx.x; i < end; i += 256) {
        int2 r = rec[i];
        int row = r.x & 0x1FFFF;
        int rank = (int)(((unsigned)r.x) >> 17);
        csr_col[rowptr[row] + rank] = r.y;
    }
}

// ---- 6. aggregation: one wave per node, 4 edge slots x unroll 2 ----
__global__ __launch_bounds__(256) void k_agg(const int* __restrict__ rowptr,
                                             const int* __restrict__ csr_col,
                                             const float* __restrict__ a_src,
                                             const float* __restrict__ a_dst,
                                             const _Float16* __restrict__ xwh,
                                             float* __restrict__ out, int N) {
    int lane = threadIdx.x & 63;
    int n = blockIdx.x * 4 + (threadIdx.x >> 6);
    if (n >= N) return;
    int beg = rowptr[n], end = rowptr[n + 1];
    int q = lane >> 4;        // edge slot 0..3
    int l = lane & 15;        // channels 8l..8l+7
    int h = l >> 2;           // head
    float s_n = a_src[(size_t)n * 4 + h];
    float acc[8] = {0, 0, 0, 0, 0, 0, 0, 0};
    float ws = 0.f;
    int last = end - 1;
    for (int i = beg; i < end; i += 8) {
        int e0 = i + q;
        int e1 = i + 4 + q;
        int e0c = e0 <= last ? e0 : last;
        int e1c = e1 <= last ? e1 : last;
        float m0 = e0 <= last ? 1.f : 0.f;
        float m1 = e1 <= last ? 1.f : 0.f;
        int c0 = csr_col[e0c];
        int c1 = csr_col[e1c];
        float w0 = m0 * lrelu_exp(s_n + a_dst[(size_t)c0 * 4 + h]);
        float w1 = m1 * lrelu_exp(s_n + a_dst[(size_t)c1 * 4 + h]);
        half8 x0 = *(const half8*)&xwh[(size_t)c0 * 128 + (l << 3)];
        half8 x1 = *(const half8*)&xwh[(size_t)c1 * 128 + (l << 3)];
        #pragma unroll
        for (int j = 0; j < 8; ++j)
            acc[j] += w0 * (float)x0[j] + w1 * (float)x1[j];
        ws += w0 + w1;
    }
    #pragma unroll
    for (int j = 0; j < 8; ++j) {
        acc[j] += __shfl_xor(acc[j], 16);
        acc[j] += __shfl_xor(acc[j], 32);
    }
    ws += __shfl_xor(ws, 16);
    ws += __shfl_xor(ws, 32);
    if (q == 0) {
        float inv = 1.0f / (ws + 1e-16f);
        float4 o0 = {acc[0] * inv, acc[1] * inv, acc[2] * inv, acc[3] * inv};
        float4 o1 = {acc[4] * inv, acc[5] * inv, acc[6] * inv, acc[7] * inv};
        *(float4*)&out[(size_t)n * 128 + (l << 3)]     = o0;
        *(float4*)&out[(size_t)n * 128 + (l << 3) + 4] = o1;
    }
}

extern "C" void kernel_launch(void* const* d_in, const int* in_sizes, int n_in,
                              void* d_out, int out_size, void* d_ws, size_t ws_size,
                              hipStream_t stream) {
    const float* x       = (const float*)d_in[0];
    const float* W       = (const float*)d_in[1];
    const float* att_src = (const float*)d_in[2];
    const float* att_dst = (const float*)d_in[3];
    // d_in[4] edge_weight: unused by the reference
    const int* eidx      = (const int*)d_in[5];
    int N = in_sizes[0] / 128;
    int E = in_sizes[4];
    float* out = (float*)d_out;

    char* p = (char*)d_ws;
    auto alloc = [&](size_t bytes) {
        char* r = p;
        p += (bytes + 255) & ~(size_t)255;
        return r;
    };
    _Float16* xwh        = (_Float16*)alloc((size_t)N * 128 * 2);
    float* a_src         = (float*)alloc((size_t)N * 4 * 4);
    float* a_dst         = (float*)alloc((size_t)N * 4 * 4);
    int*   deg           = (int*)  alloc((size_t)N * 4);
    int*   rowptr        = (int*)  alloc((size_t)(N + 1) * 4);
    int*   bcur          = (int*)  alloc(256 * 4);
    unsigned short* erank= (unsigned short*)alloc((size_t)E * 2);
    int2*  rec           = (int2*) alloc((size_t)E * 8);
    int*   csr_col       = (int*)  alloc((size_t)E * 4);

    int nbuckets = (N + 511) >> 9;
    hipMemsetAsync(deg, 0, (size_t)N * 4, stream);
    k_gemm<<<(N + 63) / 64, 256, 0, stream>>>(x, W, att_src, att_dst, xwh, a_src, a_dst, N);
    k_deg<<<(E + 255) / 256, 256, 0, stream>>>(eidx, deg, erank, E);
    k_scan<<<1, 1024, 0, stream>>>(deg, rowptr, bcur, N);
    k_part<<<(E + PCHUNK - 1) / PCHUNK, 256, 0, stream>>>(eidx, erank, bcur, rec, E);
    k_csr<<<nbuckets, 256, 0, stream>>>(rec, rowptr, csr_col, N);
    k_agg<<<(N + 3) / 4, 256, 0, stream>>>(rowptr, csr_col, a_src, a_dst, xwh, out, N);
}